// Round 12
// baseline (1271.194 us; speedup 1.0000x reference)
//
#include <hip/hip_runtime.h>
#include <hip/hip_bf16.h>

#define NN 80000
#define EE 320000
#define ET 400000   // EE + NN self loops
#define BB 3200
#define LL 5
#define NBLK 313     // ceil(NN/256)
#define MLPB 1250    // NN/64 row-blocks for fused MLP

typedef __attribute__((ext_vector_type(8))) short bf16x8;
typedef __attribute__((ext_vector_type(8))) unsigned short u16x8;
typedef __attribute__((ext_vector_type(4))) float f32x4;

__device__ __forceinline__ float bf2f(unsigned short u) {
    unsigned int v = ((unsigned int)u) << 16;
    return __builtin_bit_cast(float, v);
}
__device__ __forceinline__ unsigned short f2bf(float f) {
    return __builtin_bit_cast(unsigned short, __float2bfloat16(f));
}

// ---------------- preprocessing ----------------

__global__ void k_deg(const int* ei, int* deg) {
    int e = blockIdx.x * 256 + threadIdx.x;
    if (e >= ET) return;
    int d = (e < EE) ? ei[EE + e] : (e - EE);
    atomicAdd(&deg[d], 1);
}

__global__ void k_scan1(const int* deg, int* blksum) {
    __shared__ int sh[256];
    int t = threadIdx.x, b = blockIdx.x;
    int i = b * 256 + t;
    int v = (i < NN) ? deg[i] : 0;
    sh[t] = v; __syncthreads();
    for (int off = 128; off > 0; off >>= 1) {
        if (t < off) sh[t] += sh[t + off];
        __syncthreads();
    }
    if (t == 0) blksum[b] = sh[0];
}

__global__ __launch_bounds__(512) void k_scan2(const int* blksum, int* blkoff) {
    __shared__ int sh[512];
    int t = threadIdx.x;
    int v = (t < NBLK) ? blksum[t] : 0;
    sh[t] = v; __syncthreads();
    for (int off = 1; off < 512; off <<= 1) {
        int x = (t >= off) ? sh[t - off] : 0;
        __syncthreads();
        sh[t] += x;
        __syncthreads();
    }
    if (t < NBLK) blkoff[t] = sh[t] - v;   // exclusive
}

__global__ void k_scan3(const int* deg, const int* blkoff, int* row_start, int* cursor) {
    __shared__ int sh[256];
    int t = threadIdx.x, b = blockIdx.x;
    int i = b * 256 + t;
    int v = (i < NN) ? deg[i] : 0;
    sh[t] = v; __syncthreads();
    for (int off = 1; off < 256; off <<= 1) {
        int x = (t >= off) ? sh[t - off] : 0;
        __syncthreads();
        sh[t] += x;
        __syncthreads();
    }
    int exc = sh[t] - v + blkoff[b];
    if (i < NN) { row_start[i] = exc; cursor[i] = exc; }
    if (i == NN - 1) row_start[NN] = exc + v;
}

__global__ void k_fill(const int* ei, const int* ea, int* cursor, int* eid, int* combo) {
    int e = blockIdx.x * 256 + threadIdx.x;
    if (e >= ET) return;
    int d = (e < EE) ? ei[EE + e] : (e - EE);
    int p = atomicAdd(&cursor[d], 1);
    eid[p] = e;
    int c;
    if (e < EE) c = ea[e * 3 + 0] * 12 + ea[e * 3 + 1] * 2 + ea[e * 3 + 2];
    else        c = 22 * 12;   // self loop attr [22,0,0]
    combo[e] = c;
}

// deterministic edge order within each node bucket (atomics fill in random order)
__global__ void k_sortbkt(const int* row_start, int* eid) {
    int v = blockIdx.x * 256 + threadIdx.x;
    if (v >= NN) return;
    int s0 = row_start[v], s1 = row_start[v + 1];
    for (int i = s0 + 1; i < s1; i++) {
        int key = eid[i];
        int j = i - 1;
        while (j >= s0 && eid[j] > key) { eid[j + 1] = eid[j]; j--; }
        eid[j + 1] = key;
    }
}

// flatten eid indirection: csrc[p]=source node, ccomb[p]=edge combo, in CSR order
__global__ void k_remap(const int* eid, const int* combo, const int* ei_src,
                        int* csrc, int* ccomb) {
    int p = blockIdx.x * 256 + threadIdx.x;
    if (p >= ET) return;
    int e = eid[p];
    csrc[p]  = (e < EE) ? ei_src[e] : (e - EE);
    ccomb[p] = combo[e];
}

__global__ void k_ecomb(const float* e1, const float* e2, const float* e3, float* ec) {
    int l = blockIdx.x / 300, c = blockIdx.x % 300, d = threadIdx.x;
    int a0 = c / 12, a1 = (c / 2) % 6, a2 = c & 1;
    ec[(size_t)(l * 300 + c) * 256 + d] =
        e1[(size_t)(l * 25 + a0) * 256 + d] +
        e2[(size_t)(l * 6 + a1) * 256 + d] +
        e3[(size_t)(l * 2 + a2) * 256 + d];
}

// W1: [L][256][512] -> hi/lo bf16 pair in [L][512][256] layout (transposed)
__global__ void k_w1t(const float* W, __hip_bfloat16* Whi, __hip_bfloat16* Wlo) {
    int i = blockIdx.x * 256 + threadIdx.x;
    if (i >= LL * 512 * 256) return;
    int l = i / (512 * 256); int r = i % (512 * 256); int n = r / 256; int k = r % 256;
    float w = W[(size_t)(l * 256 + k) * 512 + n];
    unsigned short hi = f2bf(w);
    Whi[i] = __float2bfloat16(w);
    Wlo[i] = __float2bfloat16(w - bf2f(hi));
}
// W2: [L][512][256] -> hi/lo bf16 pair in [L][256][512] layout (transposed)
__global__ void k_w2t(const float* W, __hip_bfloat16* Whi, __hip_bfloat16* Wlo) {
    int i = blockIdx.x * 256 + threadIdx.x;
    if (i >= LL * 256 * 512) return;
    int l = i / (256 * 512); int r = i % (256 * 512); int n = r / 512; int k = r % 512;
    float w = W[(size_t)(l * 512 + k) * 256 + n];
    unsigned short hi = f2bf(w);
    Whi[i] = __float2bfloat16(w);
    Wlo[i] = __float2bfloat16(w - bf2f(hi));
}

__global__ void k_nodeemb(const int* x, const float* emb, __hip_bfloat16* h) {
    const int offs[9] = {0, 121, 129, 141, 156, 166, 175, 182, 185};
    int i = blockIdx.x; int d = threadIdx.x;
    float acc = 0.f;
#pragma unroll
    for (int c = 0; c < 9; c++) {
        int idx = x[i * 9 + c] + offs[c];
        acc += emb[(size_t)idx * 256 + d];
    }
    h[(size_t)i * 256 + d] = __float2bfloat16(acc);
}

// ---------------- per-layer ----------------

// 2 nodes per wave: lanes 0-31 -> node A, 32-63 -> node B; 8 cols (16B) per lane.
// Unroll-by-2 over edges; terms added in original order -> bit-identical.
__global__ __launch_bounds__(256) void k_aggr(const __hip_bfloat16* h, const float* ecomb_l,
        const int* row_start, const int* csrc, const int* ccomb,
        __hip_bfloat16* aggrB) {
    int wid = threadIdx.x >> 6;
    int lane = threadIdx.x & 63;
    int v = blockIdx.x * 8 + wid * 2 + (lane >> 5);   // NN=80000 = 10000*8, always valid
    int sl = lane & 31;
    int s0 = row_start[v], s1 = row_start[v + 1];
    const unsigned short* hp = (const unsigned short*)h;
    float acc[8] = {0.f, 0.f, 0.f, 0.f, 0.f, 0.f, 0.f, 0.f};
    int p = s0;
    for (; p + 2 <= s1; p += 2) {
        int sA = csrc[p],     cA = ccomb[p];
        int sB = csrc[p + 1], cB = ccomb[p + 1];
        u16x8 hA = *(const u16x8*)(hp + (size_t)sA * 256 + sl * 8);
        u16x8 hB = *(const u16x8*)(hp + (size_t)sB * 256 + sl * 8);
        f32x4 eA0 = *(const f32x4*)(ecomb_l + (size_t)cA * 256 + sl * 8);
        f32x4 eA1 = *(const f32x4*)(ecomb_l + (size_t)cA * 256 + sl * 8 + 4);
        f32x4 eB0 = *(const f32x4*)(ecomb_l + (size_t)cB * 256 + sl * 8);
        f32x4 eB1 = *(const f32x4*)(ecomb_l + (size_t)cB * 256 + sl * 8 + 4);
        float tA[8] = { bf2f(hA[0]) + eA0.x, bf2f(hA[1]) + eA0.y,
                        bf2f(hA[2]) + eA0.z, bf2f(hA[3]) + eA0.w,
                        bf2f(hA[4]) + eA1.x, bf2f(hA[5]) + eA1.y,
                        bf2f(hA[6]) + eA1.z, bf2f(hA[7]) + eA1.w };
        float tB[8] = { bf2f(hB[0]) + eB0.x, bf2f(hB[1]) + eB0.y,
                        bf2f(hB[2]) + eB0.z, bf2f(hB[3]) + eB0.w,
                        bf2f(hB[4]) + eB1.x, bf2f(hB[5]) + eB1.y,
                        bf2f(hB[6]) + eB1.z, bf2f(hB[7]) + eB1.w };
#pragma unroll
        for (int j = 0; j < 8; j++) { acc[j] += tA[j]; acc[j] += tB[j]; }
    }
    if (p < s1) {
        int s = csrc[p], c = ccomb[p];
        u16x8 hv = *(const u16x8*)(hp + (size_t)s * 256 + sl * 8);
        f32x4 e0 = *(const f32x4*)(ecomb_l + (size_t)c * 256 + sl * 8);
        f32x4 e1 = *(const f32x4*)(ecomb_l + (size_t)c * 256 + sl * 8 + 4);
        acc[0] += bf2f(hv[0]) + e0.x;
        acc[1] += bf2f(hv[1]) + e0.y;
        acc[2] += bf2f(hv[2]) + e0.z;
        acc[3] += bf2f(hv[3]) + e0.w;
        acc[4] += bf2f(hv[4]) + e1.x;
        acc[5] += bf2f(hv[5]) + e1.y;
        acc[6] += bf2f(hv[6]) + e1.z;
        acc[7] += bf2f(hv[7]) + e1.w;
    }
    u16x8 o;
#pragma unroll
    for (int j = 0; j < 8; j++) o[j] = f2bf(acc[j]);
    *(u16x8*)((unsigned short*)aggrB + (size_t)v * 256 + sl * 8) = o;
}

// Fused MLP, dual-bf16 (hi+lo) weights.
// Round-11 diagnosis: VGPR_Count=128 AGAIN — with launch_bounds(512) and no
// min-waves arg, hipcc targets 128 VGPR for 512-thr blocks even though 96KB LDS
// already caps us at 1 block/CU (2 waves/SIMD, which may use 256 VGPR). The
// named 2-deep weight pipeline (~150 regs live) was folded by the allocator ->
// loads serialized -> latency-bound (Mfma 18.7%, HBM 9.6%). Fix: launch_bounds
// (512, 1) to unlock the 256-VGPR budget; occupancy is unchanged (LDS-capped).
template<bool LAST>
__global__ __launch_bounds__(512, 1) void k_mlp(const __hip_bfloat16* aggrB,
        const __hip_bfloat16* W1hi, const __hip_bfloat16* W1lo, const float* b1v,
        const __hip_bfloat16* W2hi, const __hip_bfloat16* W2lo, const float* b2v,
        float* h2, float* psum, float* psq) {
    __shared__ short sAct[64 * 512];   // 64KB, 16B-slot XOR swizzled
    __shared__ short sA[64 * 256];     // 32KB, 16B-slot XOR swizzled
    int tid = threadIdx.x;
    int wave = tid >> 6, lane = tid & 63;
    int lr = lane & 15, lk = lane >> 4;
    int mBase = blockIdx.x * 64;

    // ---- stage A[64][256] once: rows mBase..+63 are contiguous 32KB in aggrB.
    // LDS linear dest (HW: base + lane*16); global source pre-swizzled so that
    // LDS[r][slot] = A[r][slot ^ (r&7)] (16B slots, 32 per row).
    {
        const char* srcBase = (const char*)aggrB + (size_t)mBase * 512;
#pragma unroll
        for (int i = 0; i < 4; i++) {
            int flatBase = wave * 4096 + i * 1024;          // uniform per wave
            int flat = flatBase + lane * 16;                 // this lane's dest
            int r = flat >> 9;
            int slot = (flat >> 4) & 31;
            int srcf = (r << 9) | (((slot ^ (r & 7)) & 31) << 4);
            __builtin_amdgcn_global_load_lds(
                (const __attribute__((address_space(1))) unsigned int*)(srcBase + srcf),
                (__attribute__((address_space(3))) unsigned int*)((char*)sA + flatBase),
                16, 0, 0);
        }
    }
    __syncthreads();

    // ---- GEMM1: act[64][512]; wave owns cols [wave*64, wave*64+64) ----
    const short* B1h = (const short*)W1hi + (size_t)(wave * 64 + lr) * 256 + lk * 8;
    const short* B1l = (const short*)W1lo + (size_t)(wave * 64 + lr) * 256 + lk * 8;
    f32x4 acc1[4][4] = {};
    bf16x8 whP[4], wlP[4], whN[4], wlN[4];
    const char* sAb = (const char*)sA;

#define LDW1(WH, WL, T) do { const int _k = (T) * 32;                              \
    _Pragma("unroll") for (int n = 0; n < 4; n++) {                                \
        WH[n] = *(const bf16x8*)(B1h + (size_t)n * 4096 + _k);                     \
        WL[n] = *(const bf16x8*)(B1l + (size_t)n * 4096 + _k); } } while (0)

#define MM1(WH, WL, T) do { const int _kt = (T); bf16x8 _a[4];                     \
    _Pragma("unroll") for (int m = 0; m < 4; m++) { int _r = m * 16 + lr;          \
        _a[m] = *(const bf16x8*)(sAb + _r * 512 + (((_kt * 4 + lk) ^ (_r & 7)) & 31) * 16); } \
    _Pragma("unroll") for (int m = 0; m < 4; m++)                                  \
    _Pragma("unroll") for (int n = 0; n < 4; n++) {                                \
        acc1[m][n] = __builtin_amdgcn_mfma_f32_16x16x32_bf16(WH[n], _a[m], acc1[m][n], 0, 0, 0); \
        acc1[m][n] = __builtin_amdgcn_mfma_f32_16x16x32_bf16(WL[n], _a[m], acc1[m][n], 0, 0, 0); } } while (0)

    LDW1(whP, wlP, 0);
    LDW1(whN, wlN, 1);
    MM1(whP, wlP, 0); LDW1(whP, wlP, 2);
    MM1(whN, wlN, 1); LDW1(whN, wlN, 3);
    MM1(whP, wlP, 2); LDW1(whP, wlP, 4);
    MM1(whN, wlN, 3); LDW1(whN, wlN, 5);
    MM1(whP, wlP, 4); LDW1(whP, wlP, 6);
    MM1(whN, wlN, 5); LDW1(whN, wlN, 7);
    MM1(whP, wlP, 6);
    MM1(whN, wlN, 7);

    // epilogue: swapped layout -> thread holds 4 consecutive cols for row m*16+lr
#pragma unroll
    for (int n = 0; n < 4; n++) {
        int col0 = wave * 64 + n * 16 + lk * 4;
        f32x4 bi = *(const f32x4*)(b1v + col0);
        int cb = col0 >> 3, ci = col0 & 7;
#pragma unroll
        for (int m = 0; m < 4; m++) {
            int row = m * 16 + lr;
            short4 o;
            o.x = (short)f2bf(fmaxf(acc1[m][n][0] + bi.x, 0.f));
            o.y = (short)f2bf(fmaxf(acc1[m][n][1] + bi.y, 0.f));
            o.z = (short)f2bf(fmaxf(acc1[m][n][2] + bi.z, 0.f));
            o.w = (short)f2bf(fmaxf(acc1[m][n][3] + bi.w, 0.f));
            *(short4*)(&sAct[row * 512 + (((cb ^ (row & 7)) << 3) | ci)]) = o;
        }
    }
    __syncthreads();

    // ---- GEMM2: h2[64][256]; wave owns cols [wave*32, wave*32+32) ----
    const short* B2h = (const short*)W2hi + (size_t)(wave * 32 + lr) * 512 + lk * 8;
    const short* B2l = (const short*)W2lo + (size_t)(wave * 32 + lr) * 512 + lk * 8;
    f32x4 acc2[4][2] = {};
    bf16x8 a2P[4], w2hP[2], w2lP[2], a2N[4], w2hN[2], w2lN[2];

#define LD2(AA, WH, WL, T) do { const int _t = (T); const int _kb = _t * 4 + lk;   \
    _Pragma("unroll") for (int m = 0; m < 4; m++) { int _row = m * 16 + lr;        \
        AA[m] = *(const bf16x8*)(&sAct[_row * 512 + ((_kb ^ (_row & 7)) << 3)]); } \
    _Pragma("unroll") for (int n = 0; n < 2; n++) {                                \
        WH[n] = *(const bf16x8*)(B2h + (size_t)n * 8192 + _t * 32);                \
        WL[n] = *(const bf16x8*)(B2l + (size_t)n * 8192 + _t * 32); } } while (0)

#define MM2(AA, WH, WL)                                                            \
    _Pragma("unroll") for (int m = 0; m < 4; m++)                                  \
    _Pragma("unroll") for (int n = 0; n < 2; n++) {                                \
        acc2[m][n] = __builtin_amdgcn_mfma_f32_16x16x32_bf16(AA[m], WH[n], acc2[m][n], 0, 0, 0); \
        acc2[m][n] = __builtin_amdgcn_mfma_f32_16x16x32_bf16(AA[m], WL[n], acc2[m][n], 0, 0, 0); }

    LD2(a2P, w2hP, w2lP, 0);
#pragma unroll
    for (int tt = 0; tt < 7; tt++) {
        LD2(a2N, w2hN, w2lN, 2 * tt + 1);
        MM2(a2P, w2hP, w2lP);
        LD2(a2P, w2hP, w2lP, 2 * tt + 2);
        MM2(a2N, w2hN, w2lN);
    }
    LD2(a2N, w2hN, w2lN, 15);
    MM2(a2P, w2hP, w2lP);
    MM2(a2N, w2hN, w2lN);

    float colS[2] = {0.f, 0.f}, colQ[2] = {0.f, 0.f};
#pragma unroll
    for (int m = 0; m < 4; m++)
#pragma unroll
        for (int n = 0; n < 2; n++) {
            int col = wave * 32 + n * 16 + lr;
            float bi = b2v[col];
#pragma unroll
            for (int j = 0; j < 4; j++) {
                int row = mBase + m * 16 + lk * 4 + j;
                float v = acc2[m][n][j] + bi;
                colS[n] += v; colQ[n] += v * v;
                if (!LAST || (row % 25 == 24))
                    h2[(size_t)row * 256 + col] = v;
            }
        }
#pragma unroll
    for (int n = 0; n < 2; n++) {
        colS[n] += __shfl_xor(colS[n], 16);
        colQ[n] += __shfl_xor(colQ[n], 16);
        colS[n] += __shfl_xor(colS[n], 32);
        colQ[n] += __shfl_xor(colQ[n], 32);
    }
    if (lk == 0) {
#pragma unroll
        for (int n = 0; n < 2; n++) {
            int col = wave * 32 + n * 16 + lr;
            psum[(size_t)col * MLPB + blockIdx.x] = colS[n];
            psq [(size_t)col * MLPB + blockIdx.x] = colQ[n];
        }
    }
#undef LDW1
#undef MM1
#undef LD2
#undef MM2
}

// one block per column: reduce MLPB row-block partials -> scale/shift
__global__ __launch_bounds__(256) void k_bn2(const float* psum, const float* psq,
                                             const float* g, const float* bta, float* stat) {
    __shared__ float s1[256], s2[256];
    int d = blockIdx.x; int t = threadIdx.x;
    float a = 0.f, b = 0.f;
    for (int rb = t; rb < MLPB; rb += 256) {
        a += psum[(size_t)d * MLPB + rb];
        b += psq [(size_t)d * MLPB + rb];
    }
    s1[t] = a; s2[t] = b; __syncthreads();
    for (int off = 128; off > 0; off >>= 1) {
        if (t < off) { s1[t] += s1[t + off]; s2[t] += s2[t + off]; }
        __syncthreads();
    }
    if (t == 0) {
        float mean = s1[0] / NN;
        float var = s2[0] / NN - mean * mean;
        float sc = rsqrtf(var + 1e-5f) * g[d];
        stat[d] = sc;
        stat[256 + d] = bta[d] - mean * sc;
    }
}

// vectorized: 4 f32 in, 4 bf16 out per thread; grid covers NN*256/4 threads
__global__ void k_bnapply(const float* h2, const float* stat, __hip_bfloat16* h, int relu) {
    int i = (blockIdx.x * 256 + threadIdx.x) * 4;   // over NN*256
    int d = i & 255;
    f32x4 v = *(const f32x4*)(h2 + i);
    f32x4 sc = *(const f32x4*)(stat + d);
    f32x4 sh = *(const f32x4*)(stat + 256 + d);
    float r0 = v.x * sc.x + sh.x;
    float r1 = v.y * sc.y + sh.y;
    float r2 = v.z * sc.z + sh.z;
    float r3 = v.w * sc.w + sh.w;
    if (relu) {
        r0 = fmaxf(r0, 0.f); r1 = fmaxf(r1, 0.f);
        r2 = fmaxf(r2, 0.f); r3 = fmaxf(r3, 0.f);
    }
    ushort4 o;
    o.x = f2bf(r0); o.y = f2bf(r1); o.z = f2bf(r2); o.w = f2bf(r3);
    *(ushort4*)((unsigned short*)h + i) = o;
}

// ---------------- head ----------------
// reads last-layer h2 (f32) + bnstat directly: BN applied to only the 3200 super-nodes
__global__ __launch_bounds__(128) void k_head(const float* h2, const float* stat,
        const float* HW1, const float* Hb1, const float* HW2, const float* Hb2,
        const float* HW3, const float* Hb3, float* out) {
    __shared__ float row[256], z1[128], z2[128];
    int g = blockIdx.x; int t = threadIdx.x;
    size_t node = (size_t)g * 25 + 24;
    row[t]       = h2[node * 256 + t] * stat[t] + stat[256 + t];
    row[t + 128] = h2[node * 256 + t + 128] * stat[t + 128] + stat[256 + t + 128];
    __syncthreads();
    float acc = Hb1[t];
    for (int k = 0; k < 256; k++) acc += row[k] * HW1[k * 128 + t];
    z1[t] = acc > 0.f ? acc : expm1f(acc);
    __syncthreads();
    acc = Hb2[t];
    for (int k = 0; k < 128; k++) acc += z1[k] * HW2[k * 128 + t];
    z2[t] = acc > 0.f ? acc : expm1f(acc);
    __syncthreads();
    if (t < 2) {
        acc = Hb3[t];
        for (int k = 0; k < 128; k++) acc += z2[k] * HW3[k * 2 + t];
        out[g * 2 + t] = acc;
    }
}

// ---------------- launch ----------------

extern "C" void kernel_launch(void* const* d_in, const int* in_sizes, int n_in,
                              void* d_out, int out_size, void* d_ws, size_t ws_size,
                              hipStream_t stream) {
    const int* x          = (const int*)d_in[0];
    const int* edge_index = (const int*)d_in[1];
    const int* edge_attr  = (const int*)d_in[2];
    const float* node_emb = (const float*)d_in[4];
    const float* ee1 = (const float*)d_in[5];
    const float* ee2 = (const float*)d_in[6];
    const float* ee3 = (const float*)d_in[7];
    const float* W1  = (const float*)d_in[8];
    const float* b1  = (const float*)d_in[9];
    const float* W2  = (const float*)d_in[10];
    const float* b2  = (const float*)d_in[11];
    const float* bng = (const float*)d_in[12];
    const float* bnb = (const float*)d_in[13];
    const float* HW1 = (const float*)d_in[14];
    const float* Hb1 = (const float*)d_in[15];
    const float* HW2 = (const float*)d_in[16];
    const float* Hb2 = (const float*)d_in[17];
    const float* HW3 = (const float*)d_in[18];
    const float* Hb3 = (const float*)d_in[19];
    float* out = (float*)d_out;

    char* ws = (char*)d_ws;
    size_t off = 0;
    auto alloc = [&](size_t bytes) -> char* {
        off = (off + 255) & ~(size_t)255;
        char* p = ws + off;
        off += bytes;
        return p;
    };
    int* deg       = (int*)alloc((size_t)NN * 4);
    int* cursor    = (int*)alloc((size_t)NN * 4);
    int* row_start = (int*)alloc((size_t)(NN + 1) * 4);
    int* blksum    = (int*)alloc((size_t)(NBLK + 1) * 4);
    int* blkoff    = (int*)alloc((size_t)(NBLK + 1) * 4);
    int* eid       = (int*)alloc((size_t)ET * 4);
    int* combo     = (int*)alloc((size_t)ET * 4);
    int* csrc      = (int*)alloc((size_t)ET * 4);
    int* ccomb     = (int*)alloc((size_t)ET * 4);
    float* ecomb   = (float*)alloc((size_t)LL * 300 * 256 * 4);
    __hip_bfloat16* W1hi = (__hip_bfloat16*)alloc((size_t)LL * 512 * 256 * 2);
    __hip_bfloat16* W1lo = (__hip_bfloat16*)alloc((size_t)LL * 512 * 256 * 2);
    __hip_bfloat16* W2hi = (__hip_bfloat16*)alloc((size_t)LL * 256 * 512 * 2);
    __hip_bfloat16* W2lo = (__hip_bfloat16*)alloc((size_t)LL * 256 * 512 * 2);
    __hip_bfloat16* h    = (__hip_bfloat16*)alloc((size_t)NN * 256 * 2);
    __hip_bfloat16* aggrB = (__hip_bfloat16*)alloc((size_t)NN * 256 * 2);
    float* h2     = (float*)alloc((size_t)NN * 256 * 4);
    float* psum   = (float*)alloc((size_t)256 * MLPB * 4);
    float* psq    = (float*)alloc((size_t)256 * MLPB * 4);
    float* bnstat = (float*)alloc((size_t)512 * 4);

    hipMemsetAsync(deg, 0, (size_t)NN * 4, stream);
    k_deg<<<(ET + 255) / 256, 256, 0, stream>>>(edge_index, deg);
    k_scan1<<<NBLK, 256, 0, stream>>>(deg, blksum);
    k_scan2<<<1, 512, 0, stream>>>(blksum, blkoff);
    k_scan3<<<NBLK, 256, 0, stream>>>(deg, blkoff, row_start, cursor);
    k_fill<<<(ET + 255) / 256, 256, 0, stream>>>(edge_index, edge_attr, cursor, eid, combo);
    k_sortbkt<<<(NN + 255) / 256, 256, 0, stream>>>(row_start, eid);
    k_remap<<<(ET + 255) / 256, 256, 0, stream>>>(eid, combo, edge_index, csrc, ccomb);
    k_ecomb<<<LL * 300, 256, 0, stream>>>(ee1, ee2, ee3, ecomb);
    k_w1t<<<(LL * 512 * 256 + 255) / 256, 256, 0, stream>>>(W1, W1hi, W1lo);
    k_w2t<<<(LL * 256 * 512 + 255) / 256, 256, 0, stream>>>(W2, W2hi, W2lo);
    k_nodeemb<<<NN, 256, 0, stream>>>(x, node_emb, h);

    for (int l = 0; l < LL; l++) {
        k_aggr<<<NN / 8, 256, 0, stream>>>(h, ecomb + (size_t)l * 300 * 256, row_start,
                                           csrc, ccomb, aggrB);
        if (l < LL - 1) {
            k_mlp<false><<<MLPB, 512, 0, stream>>>(aggrB,
                W1hi + (size_t)l * 512 * 256, W1lo + (size_t)l * 512 * 256, b1 + l * 512,
                W2hi + (size_t)l * 256 * 512, W2lo + (size_t)l * 256 * 512, b2 + l * 256,
                h2, psum, psq);
        } else {
            k_mlp<true><<<MLPB, 512, 0, stream>>>(aggrB,
                W1hi + (size_t)l * 512 * 256, W1lo + (size_t)l * 512 * 256, b1 + l * 512,
                W2hi + (size_t)l * 256 * 512, W2lo + (size_t)l * 256 * 512, b2 + l * 256,
                h2, psum, psq);
        }
        k_bn2<<<256, 256, 0, stream>>>(psum, psq, bng + l * 256, bnb + l * 256, bnstat);
        if (l < LL - 1)
            k_bnapply<<<NN * 256 / (256 * 4), 256, 0, stream>>>(h2, bnstat, h, 1);
    }

    k_head<<<BB, 128, 0, stream>>>(h2, bnstat, HW1, Hb1, HW2, Hb2, HW3, Hb3, out);
}

// Round 13
// 1108.856 us; speedup vs baseline: 1.1464x; 1.1464x over previous
//
#include <hip/hip_runtime.h>
#include <hip/hip_bf16.h>

#define NN 80000
#define EE 320000
#define ET 400000   // EE + NN self loops
#define BB 3200
#define LL 5
#define NBLK 313     // ceil(NN/256)
#define MLPB 1250    // NN/64 row-blocks for fused MLP

typedef __attribute__((ext_vector_type(8))) short bf16x8;
typedef __attribute__((ext_vector_type(8))) unsigned short u16x8;
typedef __attribute__((ext_vector_type(4))) float f32x4;

__device__ __forceinline__ float bf2f(unsigned short u) {
    unsigned int v = ((unsigned int)u) << 16;
    return __builtin_bit_cast(float, v);
}
__device__ __forceinline__ unsigned short f2bf(float f) {
    return __builtin_bit_cast(unsigned short, __float2bfloat16(f));
}

#define GLL16(SRC, DST) __builtin_amdgcn_global_load_lds( \
    (const __attribute__((address_space(1))) unsigned int*)(SRC), \
    (__attribute__((address_space(3))) unsigned int*)(DST), 16, 0, 0)

// ---------------- preprocessing ----------------

__global__ void k_deg(const int* ei, int* deg) {
    int e = blockIdx.x * 256 + threadIdx.x;
    if (e >= ET) return;
    int d = (e < EE) ? ei[EE + e] : (e - EE);
    atomicAdd(&deg[d], 1);
}

__global__ void k_scan1(const int* deg, int* blksum) {
    __shared__ int sh[256];
    int t = threadIdx.x, b = blockIdx.x;
    int i = b * 256 + t;
    int v = (i < NN) ? deg[i] : 0;
    sh[t] = v; __syncthreads();
    for (int off = 128; off > 0; off >>= 1) {
        if (t < off) sh[t] += sh[t + off];
        __syncthreads();
    }
    if (t == 0) blksum[b] = sh[0];
}

__global__ __launch_bounds__(512) void k_scan2(const int* blksum, int* blkoff) {
    __shared__ int sh[512];
    int t = threadIdx.x;
    int v = (t < NBLK) ? blksum[t] : 0;
    sh[t] = v; __syncthreads();
    for (int off = 1; off < 512; off <<= 1) {
        int x = (t >= off) ? sh[t - off] : 0;
        __syncthreads();
        sh[t] += x;
        __syncthreads();
    }
    if (t < NBLK) blkoff[t] = sh[t] - v;   // exclusive
}

__global__ void k_scan3(const int* deg, const int* blkoff, int* row_start, int* cursor) {
    __shared__ int sh[256];
    int t = threadIdx.x, b = blockIdx.x;
    int i = b * 256 + t;
    int v = (i < NN) ? deg[i] : 0;
    sh[t] = v; __syncthreads();
    for (int off = 1; off < 256; off <<= 1) {
        int x = (t >= off) ? sh[t - off] : 0;
        __syncthreads();
        sh[t] += x;
        __syncthreads();
    }
    int exc = sh[t] - v + blkoff[b];
    if (i < NN) { row_start[i] = exc; cursor[i] = exc; }
    if (i == NN - 1) row_start[NN] = exc + v;
}

__global__ void k_fill(const int* ei, const int* ea, int* cursor, int* eid, int* combo) {
    int e = blockIdx.x * 256 + threadIdx.x;
    if (e >= ET) return;
    int d = (e < EE) ? ei[EE + e] : (e - EE);
    int p = atomicAdd(&cursor[d], 1);
    eid[p] = e;
    int c;
    if (e < EE) c = ea[e * 3 + 0] * 12 + ea[e * 3 + 1] * 2 + ea[e * 3 + 2];
    else        c = 22 * 12;   // self loop attr [22,0,0]
    combo[e] = c;
}

// deterministic edge order within each node bucket (atomics fill in random order)
__global__ void k_sortbkt(const int* row_start, int* eid) {
    int v = blockIdx.x * 256 + threadIdx.x;
    if (v >= NN) return;
    int s0 = row_start[v], s1 = row_start[v + 1];
    for (int i = s0 + 1; i < s1; i++) {
        int key = eid[i];
        int j = i - 1;
        while (j >= s0 && eid[j] > key) { eid[j + 1] = eid[j]; j--; }
        eid[j + 1] = key;
    }
}

// flatten eid indirection: csrc[p]=source node, ccomb[p]=edge combo, in CSR order
__global__ void k_remap(const int* eid, const int* combo, const int* ei_src,
                        int* csrc, int* ccomb) {
    int p = blockIdx.x * 256 + threadIdx.x;
    if (p >= ET) return;
    int e = eid[p];
    csrc[p]  = (e < EE) ? ei_src[e] : (e - EE);
    ccomb[p] = combo[e];
}

__global__ void k_ecomb(const float* e1, const float* e2, const float* e3, float* ec) {
    int l = blockIdx.x / 300, c = blockIdx.x % 300, d = threadIdx.x;
    int a0 = c / 12, a1 = (c / 2) % 6, a2 = c & 1;
    ec[(size_t)(l * 300 + c) * 256 + d] =
        e1[(size_t)(l * 25 + a0) * 256 + d] +
        e2[(size_t)(l * 6 + a1) * 256 + d] +
        e3[(size_t)(l * 2 + a2) * 256 + d];
}

// W1: [L][256][512] -> hi/lo bf16 pair in [L][512][256] layout (transposed)
__global__ void k_w1t(const float* W, __hip_bfloat16* Whi, __hip_bfloat16* Wlo) {
    int i = blockIdx.x * 256 + threadIdx.x;
    if (i >= LL * 512 * 256) return;
    int l = i / (512 * 256); int r = i % (512 * 256); int n = r / 256; int k = r % 256;
    float w = W[(size_t)(l * 256 + k) * 512 + n];
    unsigned short hi = f2bf(w);
    Whi[i] = __float2bfloat16(w);
    Wlo[i] = __float2bfloat16(w - bf2f(hi));
}
// W2: [L][512][256] -> hi/lo bf16 pair in [L][256][512] layout (transposed)
__global__ void k_w2t(const float* W, __hip_bfloat16* Whi, __hip_bfloat16* Wlo) {
    int i = blockIdx.x * 256 + threadIdx.x;
    if (i >= LL * 256 * 512) return;
    int l = i / (256 * 512); int r = i % (256 * 512); int n = r / 512; int k = r % 512;
    float w = W[(size_t)(l * 512 + k) * 256 + n];
    unsigned short hi = f2bf(w);
    Whi[i] = __float2bfloat16(w);
    Wlo[i] = __float2bfloat16(w - bf2f(hi));
}

__global__ void k_nodeemb(const int* x, const float* emb, __hip_bfloat16* h) {
    const int offs[9] = {0, 121, 129, 141, 156, 166, 175, 182, 185};
    int i = blockIdx.x; int d = threadIdx.x;
    float acc = 0.f;
#pragma unroll
    for (int c = 0; c < 9; c++) {
        int idx = x[i * 9 + c] + offs[c];
        acc += emb[(size_t)idx * 256 + d];
    }
    h[(size_t)i * 256 + d] = __float2bfloat16(acc);
}

// ---------------- per-layer ----------------

// 2 nodes per wave: lanes 0-31 -> node A, 32-63 -> node B; 8 cols (16B) per lane.
// Unroll-by-2 over edges; terms added in original order -> bit-identical.
__global__ __launch_bounds__(256) void k_aggr(const __hip_bfloat16* h, const float* ecomb_l,
        const int* row_start, const int* csrc, const int* ccomb,
        __hip_bfloat16* aggrB) {
    int wid = threadIdx.x >> 6;
    int lane = threadIdx.x & 63;
    int v = blockIdx.x * 8 + wid * 2 + (lane >> 5);   // NN=80000 = 10000*8, always valid
    int sl = lane & 31;
    int s0 = row_start[v], s1 = row_start[v + 1];
    const unsigned short* hp = (const unsigned short*)h;
    float acc[8] = {0.f, 0.f, 0.f, 0.f, 0.f, 0.f, 0.f, 0.f};
    int p = s0;
    for (; p + 2 <= s1; p += 2) {
        int sA = csrc[p],     cA = ccomb[p];
        int sB = csrc[p + 1], cB = ccomb[p + 1];
        u16x8 hA = *(const u16x8*)(hp + (size_t)sA * 256 + sl * 8);
        u16x8 hB = *(const u16x8*)(hp + (size_t)sB * 256 + sl * 8);
        f32x4 eA0 = *(const f32x4*)(ecomb_l + (size_t)cA * 256 + sl * 8);
        f32x4 eA1 = *(const f32x4*)(ecomb_l + (size_t)cA * 256 + sl * 8 + 4);
        f32x4 eB0 = *(const f32x4*)(ecomb_l + (size_t)cB * 256 + sl * 8);
        f32x4 eB1 = *(const f32x4*)(ecomb_l + (size_t)cB * 256 + sl * 8 + 4);
        float tA[8] = { bf2f(hA[0]) + eA0.x, bf2f(hA[1]) + eA0.y,
                        bf2f(hA[2]) + eA0.z, bf2f(hA[3]) + eA0.w,
                        bf2f(hA[4]) + eA1.x, bf2f(hA[5]) + eA1.y,
                        bf2f(hA[6]) + eA1.z, bf2f(hA[7]) + eA1.w };
        float tB[8] = { bf2f(hB[0]) + eB0.x, bf2f(hB[1]) + eB0.y,
                        bf2f(hB[2]) + eB0.z, bf2f(hB[3]) + eB0.w,
                        bf2f(hB[4]) + eB1.x, bf2f(hB[5]) + eB1.y,
                        bf2f(hB[6]) + eB1.z, bf2f(hB[7]) + eB1.w };
#pragma unroll
        for (int j = 0; j < 8; j++) { acc[j] += tA[j]; acc[j] += tB[j]; }
    }
    if (p < s1) {
        int s = csrc[p], c = ccomb[p];
        u16x8 hv = *(const u16x8*)(hp + (size_t)s * 256 + sl * 8);
        f32x4 e0 = *(const f32x4*)(ecomb_l + (size_t)c * 256 + sl * 8);
        f32x4 e1 = *(const f32x4*)(ecomb_l + (size_t)c * 256 + sl * 8 + 4);
        acc[0] += bf2f(hv[0]) + e0.x;
        acc[1] += bf2f(hv[1]) + e0.y;
        acc[2] += bf2f(hv[2]) + e0.z;
        acc[3] += bf2f(hv[3]) + e0.w;
        acc[4] += bf2f(hv[4]) + e1.x;
        acc[5] += bf2f(hv[5]) + e1.y;
        acc[6] += bf2f(hv[6]) + e1.z;
        acc[7] += bf2f(hv[7]) + e1.w;
    }
    u16x8 o;
#pragma unroll
    for (int j = 0; j < 8; j++) o[j] = f2bf(acc[j]);
    *(u16x8*)((unsigned short*)aggrB + (size_t)v * 256 + sl * 8) = o;
}

// Fused MLP, dual-bf16 (hi+lo) weights.
// Rounds 8-12 showed global->VGPR weight loads can't be pipelined at HIP source
// (scheduler serializes; VGPR pinned 128). Fix: stage weights via ASYNC
// global_load_lds (zero VGPR cost) double-buffered, MFMA fed from LDS (the m97/
// round-6 proven pattern). LDS 160KB aliased by phase:
//   [0,32K) sA          -> [0,64K) sAct (after GEMM1)
//   [32K,160K) W1 dbuf  -> [64K,128K) W2 dbuf
// One barrier per k-step; stage(t+1) issued BEFORE ds_read/MFMA(t).
// W granule layout XOR-swizzled (ks ^ ((n+(n>>2))&3)) -> 2-way banks (free).
// Numerics identical to rounds 8-12 (same k-order, hi->lo, same BN grouping).
template<bool LAST>
__global__ __launch_bounds__(512) void k_mlp(const __hip_bfloat16* aggrB,
        const __hip_bfloat16* W1hi, const __hip_bfloat16* W1lo, const float* b1v,
        const __hip_bfloat16* W2hi, const __hip_bfloat16* W2lo, const float* b2v,
        float* h2, float* psum, float* psq) {
    __shared__ __align__(16) char smem[160 * 1024];
    int tid = threadIdx.x;
    int wave = tid >> 6, lane = tid & 63;
    int lr = lane & 15, lk = lane >> 4;
    int mBase = blockIdx.x * 64;

    // ---- stage A[64][256] (32KB) into smem[0,32K): linear dest, swizzled source
    {
        const char* srcBase = (const char*)aggrB + (size_t)mBase * 512;
#pragma unroll
        for (int i = 0; i < 4; i++) {
            int g0 = wave * 4096 + i * 1024;     // uniform byte base per wave
            int flat = g0 + lane * 16;
            int r = flat >> 9;
            int slot = (flat >> 4) & 31;
            int srcf = (r << 9) | (((slot ^ (r & 7)) & 31) << 4);
            GLL16(srcBase + srcf, smem + g0);
        }
    }

    const char* W1hB = (const char*)W1hi;
    const char* W1lB = (const char*)W1lo;
    // W1 slice [512 n][32 k] hi+lo = 64KB; granule (n,j) holds W[n][j ^ s(n)]
    auto stageW1 = [&](int buf, int k0) {
        char* dst = smem + 32768 + buf * 65536;
#pragma unroll
        for (int i = 0; i < 4; i++) {
            int g0 = i * 512 + wave * 64;        // granule base, uniform per wave
            int g  = g0 + lane;
            int n = g >> 2, j = g & 3;
            int ks = j ^ ((n + (n >> 2)) & 3);
            size_t so = (size_t)n * 512 + (size_t)k0 * 2 + ks * 16;
            GLL16(W1hB + so, dst + g0 * 16);
            GLL16(W1lB + so, dst + 32768 + g0 * 16);
        }
    };

    stageW1(0, 0);
    __syncthreads();   // drains sA + first W1 slice

    // ---- GEMM1: act[64][512]; wave owns cols [wave*64, wave*64+64) ----
    f32x4 acc1[4][4] = {};
    for (int t = 0; t < 8; t++) {
        int cur = t & 1;
        if (t + 1 < 8) stageW1(cur ^ 1, (t + 1) * 32);   // prefetch next slice
        const char* bW = smem + 32768 + cur * 65536;
        bf16x8 wh[4], wl[4], a[4];
#pragma unroll
        for (int n = 0; n < 4; n++) {
            int n0 = wave * 64 + n * 16 + lr;
            int go = (n0 * 4 + (lk ^ ((n0 + (n0 >> 2)) & 3))) * 16;
            wh[n] = *(const bf16x8*)(bW + go);
            wl[n] = *(const bf16x8*)(bW + 32768 + go);
        }
#pragma unroll
        for (int m = 0; m < 4; m++) {
            int r = m * 16 + lr;
            a[m] = *(const bf16x8*)(smem + r * 512 + ((((t * 4 + lk) ^ (r & 7)) & 31) * 16));
        }
#pragma unroll
        for (int m = 0; m < 4; m++)
#pragma unroll
            for (int n = 0; n < 4; n++) {
                acc1[m][n] = __builtin_amdgcn_mfma_f32_16x16x32_bf16(wh[n], a[m], acc1[m][n], 0, 0, 0);
                acc1[m][n] = __builtin_amdgcn_mfma_f32_16x16x32_bf16(wl[n], a[m], acc1[m][n], 0, 0, 0);
            }
        __syncthreads();   // drains prefetch + protects buf reuse + sA/sAct alias
    }

    // epilogue: thread holds 4 consecutive act cols for row m*16+lr (swapped mfma)
    short* sAct = (short*)smem;   // [0,64K): sA and W1buf0-lower are dead
#pragma unroll
    for (int n = 0; n < 4; n++) {
        int col0 = wave * 64 + n * 16 + lk * 4;
        f32x4 bi = *(const f32x4*)(b1v + col0);
        int cb = col0 >> 3, ci = col0 & 7;
#pragma unroll
        for (int m = 0; m < 4; m++) {
            int row = m * 16 + lr;
            short4 o;
            o.x = (short)f2bf(fmaxf(acc1[m][n][0] + bi.x, 0.f));
            o.y = (short)f2bf(fmaxf(acc1[m][n][1] + bi.y, 0.f));
            o.z = (short)f2bf(fmaxf(acc1[m][n][2] + bi.z, 0.f));
            o.w = (short)f2bf(fmaxf(acc1[m][n][3] + bi.w, 0.f));
            *(short4*)(&sAct[row * 512 + (((cb ^ (row & 7)) << 3) | ci)]) = o;
        }
    }

    const char* W2hB = (const char*)W2hi;
    const char* W2lB = (const char*)W2lo;
    // W2 slice [256 n][32 k] hi+lo = 32KB
    auto stageW2 = [&](int buf, int k0) {
        char* dst = smem + 65536 + buf * 32768;
#pragma unroll
        for (int i = 0; i < 2; i++) {
            int g0 = i * 512 + wave * 64;
            int g  = g0 + lane;
            int n = g >> 2, j = g & 3;
            int ks = j ^ ((n + (n >> 2)) & 3);
            size_t so = (size_t)n * 1024 + (size_t)k0 * 2 + ks * 16;
            GLL16(W2hB + so, dst + g0 * 16);
            GLL16(W2lB + so, dst + 16384 + g0 * 16);
        }
    };
    stageW2(0, 0);
    __syncthreads();   // drains sAct writes + first W2 slice

    // ---- GEMM2: h2[64][256]; wave owns cols [wave*32, wave*32+32) ----
    f32x4 acc2[4][2] = {};
    for (int t = 0; t < 16; t++) {
        int cur = t & 1;
        if (t + 1 < 16) stageW2(cur ^ 1, (t + 1) * 32);
        const char* bW = smem + 65536 + cur * 32768;
        bf16x8 a2[4], w2h[2], w2l[2];
        int kb = t * 4 + lk;
#pragma unroll
        for (int m = 0; m < 4; m++) {
            int row = m * 16 + lr;
            a2[m] = *(const bf16x8*)((const char*)sAct + row * 1024 + (((kb ^ (row & 7)) & 63) << 4));
        }
#pragma unroll
        for (int n = 0; n < 2; n++) {
            int n0 = wave * 32 + n * 16 + lr;
            int go = (n0 * 4 + (lk ^ ((n0 + (n0 >> 2)) & 3))) * 16;
            w2h[n] = *(const bf16x8*)(bW + go);
            w2l[n] = *(const bf16x8*)(bW + 16384 + go);
        }
#pragma unroll
        for (int m = 0; m < 4; m++)
#pragma unroll
            for (int n = 0; n < 2; n++) {
                acc2[m][n] = __builtin_amdgcn_mfma_f32_16x16x32_bf16(a2[m], w2h[n], acc2[m][n], 0, 0, 0);
                acc2[m][n] = __builtin_amdgcn_mfma_f32_16x16x32_bf16(a2[m], w2l[n], acc2[m][n], 0, 0, 0);
            }
        __syncthreads();
    }

    float colS[2] = {0.f, 0.f}, colQ[2] = {0.f, 0.f};
#pragma unroll
    for (int m = 0; m < 4; m++)
#pragma unroll
        for (int n = 0; n < 2; n++) {
            int col = wave * 32 + n * 16 + lr;
            float bi = b2v[col];
#pragma unroll
            for (int j = 0; j < 4; j++) {
                int row = mBase + m * 16 + lk * 4 + j;
                float v = acc2[m][n][j] + bi;
                colS[n] += v; colQ[n] += v * v;
                if (!LAST || (row % 25 == 24))
                    h2[(size_t)row * 256 + col] = v;
            }
        }
#pragma unroll
    for (int n = 0; n < 2; n++) {
        colS[n] += __shfl_xor(colS[n], 16);
        colQ[n] += __shfl_xor(colQ[n], 16);
        colS[n] += __shfl_xor(colS[n], 32);
        colQ[n] += __shfl_xor(colQ[n], 32);
    }
    if (lk == 0) {
#pragma unroll
        for (int n = 0; n < 2; n++) {
            int col = wave * 32 + n * 16 + lr;
            psum[(size_t)col * MLPB + blockIdx.x] = colS[n];
            psq [(size_t)col * MLPB + blockIdx.x] = colQ[n];
        }
    }
}

// one block per column: reduce MLPB row-block partials -> scale/shift
__global__ __launch_bounds__(256) void k_bn2(const float* psum, const float* psq,
                                             const float* g, const float* bta, float* stat) {
    __shared__ float s1[256], s2[256];
    int d = blockIdx.x; int t = threadIdx.x;
    float a = 0.f, b = 0.f;
    for (int rb = t; rb < MLPB; rb += 256) {
        a += psum[(size_t)d * MLPB + rb];
        b += psq [(size_t)d * MLPB + rb];
    }
    s1[t] = a; s2[t] = b; __syncthreads();
    for (int off = 128; off > 0; off >>= 1) {
        if (t < off) { s1[t] += s1[t + off]; s2[t] += s2[t + off]; }
        __syncthreads();
    }
    if (t == 0) {
        float mean = s1[0] / NN;
        float var = s2[0] / NN - mean * mean;
        float sc = rsqrtf(var + 1e-5f) * g[d];
        stat[d] = sc;
        stat[256 + d] = bta[d] - mean * sc;
    }
}

// vectorized: 4 f32 in, 4 bf16 out per thread; grid covers NN*256/4 threads
__global__ void k_bnapply(const float* h2, const float* stat, __hip_bfloat16* h, int relu) {
    int i = (blockIdx.x * 256 + threadIdx.x) * 4;   // over NN*256
    int d = i & 255;
    f32x4 v = *(const f32x4*)(h2 + i);
    f32x4 sc = *(const f32x4*)(stat + d);
    f32x4 sh = *(const f32x4*)(stat + 256 + d);
    float r0 = v.x * sc.x + sh.x;
    float r1 = v.y * sc.y + sh.y;
    float r2 = v.z * sc.z + sh.z;
    float r3 = v.w * sc.w + sh.w;
    if (relu) {
        r0 = fmaxf(r0, 0.f); r1 = fmaxf(r1, 0.f);
        r2 = fmaxf(r2, 0.f); r3 = fmaxf(r3, 0.f);
    }
    ushort4 o;
    o.x = f2bf(r0); o.y = f2bf(r1); o.z = f2bf(r2); o.w = f2bf(r3);
    *(ushort4*)((unsigned short*)h + i) = o;
}

// ---------------- head ----------------
// reads last-layer h2 (f32) + bnstat directly: BN applied to only the 3200 super-nodes
__global__ __launch_bounds__(128) void k_head(const float* h2, const float* stat,
        const float* HW1, const float* Hb1, const float* HW2, const float* Hb2,
        const float* HW3, const float* Hb3, float* out) {
    __shared__ float row[256], z1[128], z2[128];
    int g = blockIdx.x; int t = threadIdx.x;
    size_t node = (size_t)g * 25 + 24;
    row[t]       = h2[node * 256 + t] * stat[t] + stat[256 + t];
    row[t + 128] = h2[node * 256 + t + 128] * stat[t + 128] + stat[256 + t + 128];
    __syncthreads();
    float acc = Hb1[t];
    for (int k = 0; k < 256; k++) acc += row[k] * HW1[k * 128 + t];
    z1[t] = acc > 0.f ? acc : expm1f(acc);
    __syncthreads();
    acc = Hb2[t];
    for (int k = 0; k < 128; k++) acc += z1[k] * HW2[k * 128 + t];
    z2[t] = acc > 0.f ? acc : expm1f(acc);
    __syncthreads();
    if (t < 2) {
        acc = Hb3[t];
        for (int k = 0; k < 128; k++) acc += z2[k] * HW3[k * 2 + t];
        out[g * 2 + t] = acc;
    }
}

// ---------------- launch ----------------

extern "C" void kernel_launch(void* const* d_in, const int* in_sizes, int n_in,
                              void* d_out, int out_size, void* d_ws, size_t ws_size,
                              hipStream_t stream) {
    const int* x          = (const int*)d_in[0];
    const int* edge_index = (const int*)d_in[1];
    const int* edge_attr  = (const int*)d_in[2];
    const float* node_emb = (const float*)d_in[4];
    const float* ee1 = (const float*)d_in[5];
    const float* ee2 = (const float*)d_in[6];
    const float* ee3 = (const float*)d_in[7];
    const float* W1  = (const float*)d_in[8];
    const float* b1  = (const float*)d_in[9];
    const float* W2  = (const float*)d_in[10];
    const float* b2  = (const float*)d_in[11];
    const float* bng = (const float*)d_in[12];
    const float* bnb = (const float*)d_in[13];
    const float* HW1 = (const float*)d_in[14];
    const float* Hb1 = (const float*)d_in[15];
    const float* HW2 = (const float*)d_in[16];
    const float* Hb2 = (const float*)d_in[17];
    const float* HW3 = (const float*)d_in[18];
    const float* Hb3 = (const float*)d_in[19];
    float* out = (float*)d_out;

    char* ws = (char*)d_ws;
    size_t off = 0;
    auto alloc = [&](size_t bytes) -> char* {
        off = (off + 255) & ~(size_t)255;
        char* p = ws + off;
        off += bytes;
        return p;
    };
    int* deg       = (int*)alloc((size_t)NN * 4);
    int* cursor    = (int*)alloc((size_t)NN * 4);
    int* row_start = (int*)alloc((size_t)(NN + 1) * 4);
    int* blksum    = (int*)alloc((size_t)(NBLK + 1) * 4);
    int* blkoff    = (int*)alloc((size_t)(NBLK + 1) * 4);
    int* eid       = (int*)alloc((size_t)ET * 4);
    int* combo     = (int*)alloc((size_t)ET * 4);
    int* csrc      = (int*)alloc((size_t)ET * 4);
    int* ccomb     = (int*)alloc((size_t)ET * 4);
    float* ecomb   = (float*)alloc((size_t)LL * 300 * 256 * 4);
    __hip_bfloat16* W1hi = (__hip_bfloat16*)alloc((size_t)LL * 512 * 256 * 2);
    __hip_bfloat16* W1lo = (__hip_bfloat16*)alloc((size_t)LL * 512 * 256 * 2);
    __hip_bfloat16* W2hi = (__hip_bfloat16*)alloc((size_t)LL * 256 * 512 * 2);
    __hip_bfloat16* W2lo = (__hip_bfloat16*)alloc((size_t)LL * 256 * 512 * 2);
    __hip_bfloat16* h    = (__hip_bfloat16*)alloc((size_t)NN * 256 * 2);
    __hip_bfloat16* aggrB = (__hip_bfloat16*)alloc((size_t)NN * 256 * 2);
    float* h2     = (float*)alloc((size_t)NN * 256 * 4);
    float* psum   = (float*)alloc((size_t)256 * MLPB * 4);
    float* psq    = (float*)alloc((size_t)256 * MLPB * 4);
    float* bnstat = (float*)alloc((size_t)512 * 4);

    hipMemsetAsync(deg, 0, (size_t)NN * 4, stream);
    k_deg<<<(ET + 255) / 256, 256, 0, stream>>>(edge_index, deg);
    k_scan1<<<NBLK, 256, 0, stream>>>(deg, blksum);
    k_scan2<<<1, 512, 0, stream>>>(blksum, blkoff);
    k_scan3<<<NBLK, 256, 0, stream>>>(deg, blkoff, row_start, cursor);
    k_fill<<<(ET + 255) / 256, 256, 0, stream>>>(edge_index, edge_attr, cursor, eid, combo);
    k_sortbkt<<<(NN + 255) / 256, 256, 0, stream>>>(row_start, eid);
    k_remap<<<(ET + 255) / 256, 256, 0, stream>>>(eid, combo, edge_index, csrc, ccomb);
    k_ecomb<<<LL * 300, 256, 0, stream>>>(ee1, ee2, ee3, ecomb);
    k_w1t<<<(LL * 512 * 256 + 255) / 256, 256, 0, stream>>>(W1, W1hi, W1lo);
    k_w2t<<<(LL * 256 * 512 + 255) / 256, 256, 0, stream>>>(W2, W2hi, W2lo);
    k_nodeemb<<<NN, 256, 0, stream>>>(x, node_emb, h);

    for (int l = 0; l < LL; l++) {
        k_aggr<<<NN / 8, 256, 0, stream>>>(h, ecomb + (size_t)l * 300 * 256, row_start,
                                           csrc, ccomb, aggrB);
        if (l < LL - 1) {
            k_mlp<false><<<MLPB, 512, 0, stream>>>(aggrB,
                W1hi + (size_t)l * 512 * 256, W1lo + (size_t)l * 512 * 256, b1 + l * 512,
                W2hi + (size_t)l * 256 * 512, W2lo + (size_t)l * 256 * 512, b2 + l * 256,
                h2, psum, psq);
        } else {
            k_mlp<true><<<MLPB, 512, 0, stream>>>(aggrB,
                W1hi + (size_t)l * 512 * 256, W1lo + (size_t)l * 512 * 256, b1 + l * 512,
                W2hi + (size_t)l * 256 * 512, W2lo + (size_t)l * 256 * 512, b2 + l * 256,
                h2, psum, psq);
        }
        k_bn2<<<256, 256, 0, stream>>>(psum, psq, bng + l * 256, bnb + l * 256, bnstat);
        if (l < LL - 1)
            k_bnapply<<<NN * 256 / (256 * 4), 256, 0, stream>>>(h2, bnstat, h, 1);
    }

    k_head<<<BB, 128, 0, stream>>>(h2, bnstat, HW1, Hb1, HW2, Hb2, HW3, Hb3, out);
}

// Round 14
// 988.718 us; speedup vs baseline: 1.2857x; 1.1215x over previous
//
#include <hip/hip_runtime.h>
#include <hip/hip_bf16.h>

#define NN 80000
#define EE 320000
#define ET 400000   // EE + NN self loops
#define BB 3200
#define LL 5
#define NBLK 313    // ceil(NN/256)
#define MLPB 625    // NN/128 row-blocks for fused MLP

typedef __attribute__((ext_vector_type(8))) short bf16x8;
typedef __attribute__((ext_vector_type(8))) unsigned short u16x8;
typedef __attribute__((ext_vector_type(4))) float f32x4;

__device__ __forceinline__ float bf2f(unsigned short u) {
    unsigned int v = ((unsigned int)u) << 16;
    return __builtin_bit_cast(float, v);
}
__device__ __forceinline__ unsigned short f2bf(float f) {
    return __builtin_bit_cast(unsigned short, __float2bfloat16(f));
}

#define GLL16(SRC, DST) __builtin_amdgcn_global_load_lds( \
    (const __attribute__((address_space(1))) unsigned int*)(SRC), \
    (__attribute__((address_space(3))) unsigned int*)(DST), 16, 0, 0)

// ---------------- preprocessing ----------------

__global__ void k_deg(const int* ei, int* deg) {
    int e = blockIdx.x * 256 + threadIdx.x;
    if (e >= ET) return;
    int d = (e < EE) ? ei[EE + e] : (e - EE);
    atomicAdd(&deg[d], 1);
}

__global__ void k_scan1(const int* deg, int* blksum) {
    __shared__ int sh[256];
    int t = threadIdx.x, b = blockIdx.x;
    int i = b * 256 + t;
    int v = (i < NN) ? deg[i] : 0;
    sh[t] = v; __syncthreads();
    for (int off = 128; off > 0; off >>= 1) {
        if (t < off) sh[t] += sh[t + off];
        __syncthreads();
    }
    if (t == 0) blksum[b] = sh[0];
}

__global__ __launch_bounds__(512) void k_scan2(const int* blksum, int* blkoff) {
    __shared__ int sh[512];
    int t = threadIdx.x;
    int v = (t < NBLK) ? blksum[t] : 0;
    sh[t] = v; __syncthreads();
    for (int off = 1; off < 512; off <<= 1) {
        int x = (t >= off) ? sh[t - off] : 0;
        __syncthreads();
        sh[t] += x;
        __syncthreads();
    }
    if (t < NBLK) blkoff[t] = sh[t] - v;   // exclusive
}

__global__ void k_scan3(const int* deg, const int* blkoff, int* row_start, int* cursor) {
    __shared__ int sh[256];
    int t = threadIdx.x, b = blockIdx.x;
    int i = b * 256 + t;
    int v = (i < NN) ? deg[i] : 0;
    sh[t] = v; __syncthreads();
    for (int off = 1; off < 256; off <<= 1) {
        int x = (t >= off) ? sh[t - off] : 0;
        __syncthreads();
        sh[t] += x;
        __syncthreads();
    }
    int exc = sh[t] - v + blkoff[b];
    if (i < NN) { row_start[i] = exc; cursor[i] = exc; }
    if (i == NN - 1) row_start[NN] = exc + v;
}

__global__ void k_fill(const int* ei, const int* ea, int* cursor, int* eid, int* combo) {
    int e = blockIdx.x * 256 + threadIdx.x;
    if (e >= ET) return;
    int d = (e < EE) ? ei[EE + e] : (e - EE);
    int p = atomicAdd(&cursor[d], 1);
    eid[p] = e;
    int c;
    if (e < EE) c = ea[e * 3 + 0] * 12 + ea[e * 3 + 1] * 2 + ea[e * 3 + 2];
    else        c = 22 * 12;   // self loop attr [22,0,0]
    combo[e] = c;
}

// deterministic edge order within each node bucket (atomics fill in random order)
__global__ void k_sortbkt(const int* row_start, int* eid) {
    int v = blockIdx.x * 256 + threadIdx.x;
    if (v >= NN) return;
    int s0 = row_start[v], s1 = row_start[v + 1];
    for (int i = s0 + 1; i < s1; i++) {
        int key = eid[i];
        int j = i - 1;
        while (j >= s0 && eid[j] > key) { eid[j + 1] = eid[j]; j--; }
        eid[j + 1] = key;
    }
}

// flatten eid indirection: csrc[p]=source node, ccomb[p]=edge combo, in CSR order
__global__ void k_remap(const int* eid, const int* combo, const int* ei_src,
                        int* csrc, int* ccomb) {
    int p = blockIdx.x * 256 + threadIdx.x;
    if (p >= ET) return;
    int e = eid[p];
    csrc[p]  = (e < EE) ? ei_src[e] : (e - EE);
    ccomb[p] = combo[e];
}

__global__ void k_ecomb(const float* e1, const float* e2, const float* e3, float* ec) {
    int l = blockIdx.x / 300, c = blockIdx.x % 300, d = threadIdx.x;
    int a0 = c / 12, a1 = (c / 2) % 6, a2 = c & 1;
    ec[(size_t)(l * 300 + c) * 256 + d] =
        e1[(size_t)(l * 25 + a0) * 256 + d] +
        e2[(size_t)(l * 6 + a1) * 256 + d] +
        e3[(size_t)(l * 2 + a2) * 256 + d];
}

// W1: [L][256][512] -> hi/lo bf16 pair in [L][512][256] layout (transposed)
__global__ void k_w1t(const float* W, __hip_bfloat16* Whi, __hip_bfloat16* Wlo) {
    int i = blockIdx.x * 256 + threadIdx.x;
    if (i >= LL * 512 * 256) return;
    int l = i / (512 * 256); int r = i % (512 * 256); int n = r / 256; int k = r % 256;
    float w = W[(size_t)(l * 256 + k) * 512 + n];
    unsigned short hi = f2bf(w);
    Whi[i] = __float2bfloat16(w);
    Wlo[i] = __float2bfloat16(w - bf2f(hi));
}
// W2: [L][512][256] -> hi/lo bf16 pair in [L][256][512] layout (transposed)
__global__ void k_w2t(const float* W, __hip_bfloat16* Whi, __hip_bfloat16* Wlo) {
    int i = blockIdx.x * 256 + threadIdx.x;
    if (i >= LL * 256 * 512) return;
    int l = i / (256 * 512); int r = i % (256 * 512); int n = r / 512; int k = r % 512;
    float w = W[(size_t)(l * 512 + k) * 256 + n];
    unsigned short hi = f2bf(w);
    Whi[i] = __float2bfloat16(w);
    Wlo[i] = __float2bfloat16(w - bf2f(hi));
}

__global__ void k_nodeemb(const int* x, const float* emb, __hip_bfloat16* h) {
    const int offs[9] = {0, 121, 129, 141, 156, 166, 175, 182, 185};
    int i = blockIdx.x; int d = threadIdx.x;
    float acc = 0.f;
#pragma unroll
    for (int c = 0; c < 9; c++) {
        int idx = x[i * 9 + c] + offs[c];
        acc += emb[(size_t)idx * 256 + d];
    }
    h[(size_t)i * 256 + d] = __float2bfloat16(acc);
}

// ---------------- per-layer ----------------

// 2 nodes per wave: lanes 0-31 -> node A, 32-63 -> node B; 8 cols (16B) per lane.
// Unroll-by-2 over edges; terms added in original order -> bit-identical.
__global__ __launch_bounds__(256) void k_aggr(const __hip_bfloat16* h, const float* ecomb_l,
        const int* row_start, const int* csrc, const int* ccomb,
        __hip_bfloat16* aggrB) {
    int wid = threadIdx.x >> 6;
    int lane = threadIdx.x & 63;
    int v = blockIdx.x * 8 + wid * 2 + (lane >> 5);   // NN=80000 = 10000*8, always valid
    int sl = lane & 31;
    int s0 = row_start[v], s1 = row_start[v + 1];
    const unsigned short* hp = (const unsigned short*)h;
    float acc[8] = {0.f, 0.f, 0.f, 0.f, 0.f, 0.f, 0.f, 0.f};
    int p = s0;
    for (; p + 2 <= s1; p += 2) {
        int sA = csrc[p],     cA = ccomb[p];
        int sB = csrc[p + 1], cB = ccomb[p + 1];
        u16x8 hA = *(const u16x8*)(hp + (size_t)sA * 256 + sl * 8);
        u16x8 hB = *(const u16x8*)(hp + (size_t)sB * 256 + sl * 8);
        f32x4 eA0 = *(const f32x4*)(ecomb_l + (size_t)cA * 256 + sl * 8);
        f32x4 eA1 = *(const f32x4*)(ecomb_l + (size_t)cA * 256 + sl * 8 + 4);
        f32x4 eB0 = *(const f32x4*)(ecomb_l + (size_t)cB * 256 + sl * 8);
        f32x4 eB1 = *(const f32x4*)(ecomb_l + (size_t)cB * 256 + sl * 8 + 4);
        float tA[8] = { bf2f(hA[0]) + eA0.x, bf2f(hA[1]) + eA0.y,
                        bf2f(hA[2]) + eA0.z, bf2f(hA[3]) + eA0.w,
                        bf2f(hA[4]) + eA1.x, bf2f(hA[5]) + eA1.y,
                        bf2f(hA[6]) + eA1.z, bf2f(hA[7]) + eA1.w };
        float tB[8] = { bf2f(hB[0]) + eB0.x, bf2f(hB[1]) + eB0.y,
                        bf2f(hB[2]) + eB0.z, bf2f(hB[3]) + eB0.w,
                        bf2f(hB[4]) + eB1.x, bf2f(hB[5]) + eB1.y,
                        bf2f(hB[6]) + eB1.z, bf2f(hB[7]) + eB1.w };
#pragma unroll
        for (int j = 0; j < 8; j++) { acc[j] += tA[j]; acc[j] += tB[j]; }
    }
    if (p < s1) {
        int s = csrc[p], c = ccomb[p];
        u16x8 hv = *(const u16x8*)(hp + (size_t)s * 256 + sl * 8);
        f32x4 e0 = *(const f32x4*)(ecomb_l + (size_t)c * 256 + sl * 8);
        f32x4 e1 = *(const f32x4*)(ecomb_l + (size_t)c * 256 + sl * 8 + 4);
        acc[0] += bf2f(hv[0]) + e0.x;
        acc[1] += bf2f(hv[1]) + e0.y;
        acc[2] += bf2f(hv[2]) + e0.z;
        acc[3] += bf2f(hv[3]) + e0.w;
        acc[4] += bf2f(hv[4]) + e1.x;
        acc[5] += bf2f(hv[5]) + e1.y;
        acc[6] += bf2f(hv[6]) + e1.z;
        acc[7] += bf2f(hv[7]) + e1.w;
    }
    u16x8 o;
#pragma unroll
    for (int j = 0; j < 8; j++) o[j] = f2bf(acc[j]);
    *(u16x8*)((unsigned short*)aggrB + (size_t)v * 256 + sl * 8) = o;
}

// Fused MLP, dual-bf16 (hi+lo) weights, M=128 rows/block (2 M-tiles time-share
// each staged weight slice): halves L2 weight traffic vs M=64 (625 blocks x
// 1MB) and doubles MFMA per barrier (32/wave/phase). hi/lo are separate PHASES
// (per-acc order stays hi(k),lo(k),... -> bit-identical to rounds 8-13).
// LDS 160KB: sA 64KB [0,64K) + W1 dbuf 2x32KB [64K,128K)
//            -> sAct 128KB [0,128K) (aliased after GEMM1) + W2 dbuf 2x16KB.
// A-frags load on hi-phase, reuse registers on lo-phase.
template<bool LAST>
__global__ __launch_bounds__(512, 1) void k_mlp(const __hip_bfloat16* aggrB,
        const __hip_bfloat16* W1hi, const __hip_bfloat16* W1lo, const float* b1v,
        const __hip_bfloat16* W2hi, const __hip_bfloat16* W2lo, const float* b2v,
        float* h2, float* psum, float* psq) {
    __shared__ __align__(16) char smem[160 * 1024];
    int tid = threadIdx.x;
    int wave = tid >> 6, lane = tid & 63;
    int lr = lane & 15, lk = lane >> 4;
    int mBase = blockIdx.x * 128;

    // ---- stage A[128][256] (64KB) into smem[0,64K): linear dest, swizzled src
    {
        const char* srcBase = (const char*)aggrB + (size_t)mBase * 512;
#pragma unroll
        for (int i = 0; i < 8; i++) {
            int g0 = wave * 8192 + i * 1024;     // uniform byte base per wave
            int flat = g0 + lane * 16;
            int r = flat >> 9;
            int slot = (flat >> 4) & 31;
            int srcf = (r << 9) | (((slot ^ (r & 7)) & 31) << 4);
            GLL16(srcBase + srcf, smem + g0);
        }
    }

    // W1 phase-slice: [512 n][32 k] single precision (hi or lo) = 32KB
    auto stageW1 = [&](int buf, int k, const char* Wsel) {
        char* dst = smem + 65536 + buf * 32768;
#pragma unroll
        for (int i = 0; i < 4; i++) {
            int g0 = i * 512 + wave * 64;        // granule base, uniform per wave
            int g  = g0 + lane;
            int n = g >> 2, j = g & 3;
            int ks = j ^ ((n + (n >> 2)) & 3);
            size_t so = (size_t)n * 512 + (size_t)k * 64 + ks * 16;
            GLL16(Wsel + so, dst + g0 * 16);
        }
    };
    const char* W1sel[2] = { (const char*)W1hi, (const char*)W1lo };
    stageW1(0, 0, W1sel[0]);
    __syncthreads();   // drains sA + first W1 slice

    // ---- GEMM1: act[128][512]; wave owns cols [wave*64, +64); 16 phases ----
    f32x4 acc1[2][4][4] = {};
    bf16x8 aF[2][4];
    for (int p = 0; p < 16; p++) {
        int cur = p & 1;
        if (p + 1 < 16) stageW1(cur ^ 1, (p + 1) >> 1, W1sel[(p + 1) & 1]);
        const char* bW = smem + 65536 + cur * 32768;
        int k = p >> 1, sel = p & 1;
        bf16x8 w[4];
#pragma unroll
        for (int n = 0; n < 4; n++) {
            int n0 = wave * 64 + n * 16 + lr;
            int go = (n0 * 4 + (lk ^ ((n0 + (n0 >> 2)) & 3))) * 16;
            w[n] = *(const bf16x8*)(bW + go);
        }
        if (sel == 0) {
#pragma unroll
            for (int T = 0; T < 2; T++)
#pragma unroll
                for (int m = 0; m < 4; m++) {
                    int r = T * 64 + m * 16 + lr;
                    aF[T][m] = *(const bf16x8*)(smem + r * 512 +
                               ((((k * 4 + lk) ^ (r & 7)) & 31) * 16));
                }
        }
#pragma unroll
        for (int T = 0; T < 2; T++)
#pragma unroll
            for (int m = 0; m < 4; m++)
#pragma unroll
                for (int n = 0; n < 4; n++)
                    acc1[T][m][n] = __builtin_amdgcn_mfma_f32_16x16x32_bf16(
                        w[n], aF[T][m], acc1[T][m][n], 0, 0, 0);
        __syncthreads();   // drains prefetch + protects buf reuse
    }

    // epilogue: swapped layout -> thread holds 4 consecutive act cols per row
    short* sAct = (short*)smem;   // [0,128K): sA + W1 dbuf are dead
#pragma unroll
    for (int T = 0; T < 2; T++)
#pragma unroll
        for (int n = 0; n < 4; n++) {
            int col0 = wave * 64 + n * 16 + lk * 4;
            f32x4 bi = *(const f32x4*)(b1v + col0);
            int cb = col0 >> 3, ci = col0 & 7;
#pragma unroll
            for (int m = 0; m < 4; m++) {
                int row = T * 64 + m * 16 + lr;
                short4 o;
                o.x = (short)f2bf(fmaxf(acc1[T][m][n][0] + bi.x, 0.f));
                o.y = (short)f2bf(fmaxf(acc1[T][m][n][1] + bi.y, 0.f));
                o.z = (short)f2bf(fmaxf(acc1[T][m][n][2] + bi.z, 0.f));
                o.w = (short)f2bf(fmaxf(acc1[T][m][n][3] + bi.w, 0.f));
                *(short4*)(&sAct[row * 512 + (((cb ^ (row & 7)) << 3) | ci)]) = o;
            }
        }

    // W2 phase-slice: [256 n][32 k] single precision = 16KB
    auto stageW2 = [&](int buf, int k, const char* Wsel) {
        char* dst = smem + 131072 + buf * 16384;
#pragma unroll
        for (int i = 0; i < 2; i++) {
            int g0 = i * 512 + wave * 64;
            int g  = g0 + lane;
            int n = g >> 2, j = g & 3;
            int ks = j ^ ((n + (n >> 2)) & 3);
            size_t so = (size_t)n * 1024 + (size_t)k * 64 + ks * 16;
            GLL16(Wsel + so, dst + g0 * 16);
        }
    };
    const char* W2sel[2] = { (const char*)W2hi, (const char*)W2lo };
    stageW2(0, 0, W2sel[0]);
    __syncthreads();   // drains sAct writes + first W2 slice

    // ---- GEMM2: h2[128][256]; wave owns cols [wave*32, +32); 32 phases ----
    f32x4 acc2[2][4][2] = {};
    bf16x8 a2F[2][4];
    for (int p = 0; p < 32; p++) {
        int cur = p & 1;
        if (p + 1 < 32) stageW2(cur ^ 1, (p + 1) >> 1, W2sel[(p + 1) & 1]);
        const char* bW = smem + 131072 + cur * 16384;
        int k = p >> 1, sel = p & 1;
        bf16x8 w[2];
#pragma unroll
        for (int n = 0; n < 2; n++) {
            int n0 = wave * 32 + n * 16 + lr;
            int go = (n0 * 4 + (lk ^ ((n0 + (n0 >> 2)) & 3))) * 16;
            w[n] = *(const bf16x8*)(bW + go);
        }
        if (sel == 0) {
            int kb = k * 4 + lk;
#pragma unroll
            for (int T = 0; T < 2; T++)
#pragma unroll
                for (int m = 0; m < 4; m++) {
                    int row = T * 64 + m * 16 + lr;
                    a2F[T][m] = *(const bf16x8*)((const char*)sAct + row * 1024 +
                                (((kb ^ (row & 7)) & 63) << 4));
                }
        }
#pragma unroll
        for (int T = 0; T < 2; T++)
#pragma unroll
            for (int m = 0; m < 4; m++)
#pragma unroll
                for (int n = 0; n < 2; n++)
                    acc2[T][m][n] = __builtin_amdgcn_mfma_f32_16x16x32_bf16(
                        a2F[T][m], w[n], acc2[T][m][n], 0, 0, 0);
        __syncthreads();
    }

    float colS[2] = {0.f, 0.f}, colQ[2] = {0.f, 0.f};
#pragma unroll
    for (int T = 0; T < 2; T++)
#pragma unroll
        for (int m = 0; m < 4; m++)
#pragma unroll
            for (int n = 0; n < 2; n++) {
                int col = wave * 32 + n * 16 + lr;
                float bi = b2v[col];
#pragma unroll
                for (int j = 0; j < 4; j++) {
                    int row = mBase + T * 64 + m * 16 + lk * 4 + j;
                    float v = acc2[T][m][n][j] + bi;
                    colS[n] += v; colQ[n] += v * v;
                    if (!LAST || (row % 25 == 24))
                        h2[(size_t)row * 256 + col] = v;
                }
            }
#pragma unroll
    for (int n = 0; n < 2; n++) {
        colS[n] += __shfl_xor(colS[n], 16);
        colQ[n] += __shfl_xor(colQ[n], 16);
        colS[n] += __shfl_xor(colS[n], 32);
        colQ[n] += __shfl_xor(colQ[n], 32);
    }
    if (lk == 0) {
#pragma unroll
        for (int n = 0; n < 2; n++) {
            int col = wave * 32 + n * 16 + lr;
            psum[(size_t)col * MLPB + blockIdx.x] = colS[n];
            psq [(size_t)col * MLPB + blockIdx.x] = colQ[n];
        }
    }
}

// one block per column: reduce MLPB row-block partials -> scale/shift
__global__ __launch_bounds__(256) void k_bn2(const float* psum, const float* psq,
                                             const float* g, const float* bta, float* stat) {
    __shared__ float s1[256], s2[256];
    int d = blockIdx.x; int t = threadIdx.x;
    float a = 0.f, b = 0.f;
    for (int rb = t; rb < MLPB; rb += 256) {
        a += psum[(size_t)d * MLPB + rb];
        b += psq [(size_t)d * MLPB + rb];
    }
    s1[t] = a; s2[t] = b; __syncthreads();
    for (int off = 128; off > 0; off >>= 1) {
        if (t < off) { s1[t] += s1[t + off]; s2[t] += s2[t + off]; }
        __syncthreads();
    }
    if (t == 0) {
        float mean = s1[0] / NN;
        float var = s2[0] / NN - mean * mean;
        float sc = rsqrtf(var + 1e-5f) * g[d];
        stat[d] = sc;
        stat[256 + d] = bta[d] - mean * sc;
    }
}

// vectorized: 4 f32 in, 4 bf16 out per thread; grid covers NN*256/4 threads
__global__ void k_bnapply(const float* h2, const float* stat, __hip_bfloat16* h, int relu) {
    int i = (blockIdx.x * 256 + threadIdx.x) * 4;   // over NN*256
    int d = i & 255;
    f32x4 v = *(const f32x4*)(h2 + i);
    f32x4 sc = *(const f32x4*)(stat + d);
    f32x4 sh = *(const f32x4*)(stat + 256 + d);
    float r0 = v.x * sc.x + sh.x;
    float r1 = v.y * sc.y + sh.y;
    float r2 = v.z * sc.z + sh.z;
    float r3 = v.w * sc.w + sh.w;
    if (relu) {
        r0 = fmaxf(r0, 0.f); r1 = fmaxf(r1, 0.f);
        r2 = fmaxf(r2, 0.f); r3 = fmaxf(r3, 0.f);
    }
    ushort4 o;
    o.x = f2bf(r0); o.y = f2bf(r1); o.z = f2bf(r2); o.w = f2bf(r3);
    *(ushort4*)((unsigned short*)h + i) = o;
}

// ---------------- head ----------------
// reads last-layer h2 (f32) + bnstat directly: BN applied to only the 3200 super-nodes
__global__ __launch_bounds__(128) void k_head(const float* h2, const float* stat,
        const float* HW1, const float* Hb1, const float* HW2, const float* Hb2,
        const float* HW3, const float* Hb3, float* out) {
    __shared__ float row[256], z1[128], z2[128];
    int g = blockIdx.x; int t = threadIdx.x;
    size_t node = (size_t)g * 25 + 24;
    row[t]       = h2[node * 256 + t] * stat[t] + stat[256 + t];
    row[t + 128] = h2[node * 256 + t + 128] * stat[t + 128] + stat[256 + t + 128];
    __syncthreads();
    float acc = Hb1[t];
    for (int k = 0; k < 256; k++) acc += row[k] * HW1[k * 128 + t];
    z1[t] = acc > 0.f ? acc : expm1f(acc);
    __syncthreads();
    acc = Hb2[t];
    for (int k = 0; k < 128; k++) acc += z1[k] * HW2[k * 128 + t];
    z2[t] = acc > 0.f ? acc : expm1f(acc);
    __syncthreads();
    if (t < 2) {
        acc = Hb3[t];
        for (int k = 0; k < 128; k++) acc += z2[k] * HW3[k * 2 + t];
        out[g * 2 + t] = acc;
    }
}

// ---------------- launch ----------------

extern "C" void kernel_launch(void* const* d_in, const int* in_sizes, int n_in,
                              void* d_out, int out_size, void* d_ws, size_t ws_size,
                              hipStream_t stream) {
    const int* x          = (const int*)d_in[0];
    const int* edge_index = (const int*)d_in[1];
    const int* edge_attr  = (const int*)d_in[2];
    const float* node_emb = (const float*)d_in[4];
    const float* ee1 = (const float*)d_in[5];
    const float* ee2 = (const float*)d_in[6];
    const float* ee3 = (const float*)d_in[7];
    const float* W1  = (const float*)d_in[8];
    const float* b1  = (const float*)d_in[9];
    const float* W2  = (const float*)d_in[10];
    const float* b2  = (const float*)d_in[11];
    const float* bng = (const float*)d_in[12];
    const float* bnb = (const float*)d_in[13];
    const float* HW1 = (const float*)d_in[14];
    const float* Hb1 = (const float*)d_in[15];
    const float* HW2 = (const float*)d_in[16];
    const float* Hb2 = (const float*)d_in[17];
    const float* HW3 = (const float*)d_in[18];
    const float* Hb3 = (const float*)d_in[19];
    float* out = (float*)d_out;

    char* ws = (char*)d_ws;
    size_t off = 0;
    auto alloc = [&](size_t bytes) -> char* {
        off = (off + 255) & ~(size_t)255;
        char* p = ws + off;
        off += bytes;
        return p;
    };
    int* deg       = (int*)alloc((size_t)NN * 4);
    int* cursor    = (int*)alloc((size_t)NN * 4);
    int* row_start = (int*)alloc((size_t)(NN + 1) * 4);
    int* blksum    = (int*)alloc((size_t)(NBLK + 1) * 4);
    int* blkoff    = (int*)alloc((size_t)(NBLK + 1) * 4);
    int* eid       = (int*)alloc((size_t)ET * 4);
    int* combo     = (int*)alloc((size_t)ET * 4);
    int* csrc      = (int*)alloc((size_t)ET * 4);
    int* ccomb     = (int*)alloc((size_t)ET * 4);
    float* ecomb   = (float*)alloc((size_t)LL * 300 * 256 * 4);
    __hip_bfloat16* W1hi = (__hip_bfloat16*)alloc((size_t)LL * 512 * 256 * 2);
    __hip_bfloat16* W1lo = (__hip_bfloat16*)alloc((size_t)LL * 512 * 256 * 2);
    __hip_bfloat16* W2hi = (__hip_bfloat16*)alloc((size_t)LL * 256 * 512 * 2);
    __hip_bfloat16* W2lo = (__hip_bfloat16*)alloc((size_t)LL * 256 * 512 * 2);
    __hip_bfloat16* h    = (__hip_bfloat16*)alloc((size_t)NN * 256 * 2);
    __hip_bfloat16* aggrB = (__hip_bfloat16*)alloc((size_t)NN * 256 * 2);
    float* h2     = (float*)alloc((size_t)NN * 256 * 4);
    float* psum   = (float*)alloc((size_t)256 * MLPB * 4);
    float* psq    = (float*)alloc((size_t)256 * MLPB * 4);
    float* bnstat = (float*)alloc((size_t)512 * 4);

    hipMemsetAsync(deg, 0, (size_t)NN * 4, stream);
    k_deg<<<(ET + 255) / 256, 256, 0, stream>>>(edge_index, deg);
    k_scan1<<<NBLK, 256, 0, stream>>>(deg, blksum);
    k_scan2<<<1, 512, 0, stream>>>(blksum, blkoff);
    k_scan3<<<NBLK, 256, 0, stream>>>(deg, blkoff, row_start, cursor);
    k_fill<<<(ET + 255) / 256, 256, 0, stream>>>(edge_index, edge_attr, cursor, eid, combo);
    k_sortbkt<<<(NN + 255) / 256, 256, 0, stream>>>(row_start, eid);
    k_remap<<<(ET + 255) / 256, 256, 0, stream>>>(eid, combo, edge_index, csrc, ccomb);
    k_ecomb<<<LL * 300, 256, 0, stream>>>(ee1, ee2, ee3, ecomb);
    k_w1t<<<(LL * 512 * 256 + 255) / 256, 256, 0, stream>>>(W1, W1hi, W1lo);
    k_w2t<<<(LL * 256 * 512 + 255) / 256, 256, 0, stream>>>(W2, W2hi, W2lo);
    k_nodeemb<<<NN, 256, 0, stream>>>(x, node_emb, h);

    for (int l = 0; l < LL; l++) {
        k_aggr<<<NN / 8, 256, 0, stream>>>(h, ecomb + (size_t)l * 300 * 256, row_start,
                                           csrc, ccomb, aggrB);
        if (l < LL - 1) {
            k_mlp<false><<<MLPB, 512, 0, stream>>>(aggrB,
                W1hi + (size_t)l * 512 * 256, W1lo + (size_t)l * 512 * 256, b1 + l * 512,
                W2hi + (size_t)l * 256 * 512, W2lo + (size_t)l * 256 * 512, b2 + l * 256,
                h2, psum, psq);
        } else {
            k_mlp<true><<<MLPB, 512, 0, stream>>>(aggrB,
                W1hi + (size_t)l * 512 * 256, W1lo + (size_t)l * 512 * 256, b1 + l * 512,
                W2hi + (size_t)l * 256 * 512, W2lo + (size_t)l * 256 * 512, b2 + l * 256,
                h2, psum, psq);
        }
        k_bn2<<<256, 256, 0, stream>>>(psum, psq, bng + l * 256, bnb + l * 256, bnstat);
        if (l < LL - 1)
            k_bnapply<<<NN * 256 / (256 * 4), 256, 0, stream>>>(h2, bnstat, h, 1);
    }

    k_head<<<BB, 128, 0, stream>>>(h2, bnstat, HW1, Hb1, HW2, Hb2, HW3, Hb3, out);
}